// Round 8
// baseline (207.189 us; speedup 1.0000x reference)
//
#include <hip/hip_runtime.h>
#include <math.h>

// ToRGB fused single-kernel: y[b,o,p] = clip(sum_i c[b,o,i]*x[b,i,p]+bias[o],+-256) + up2(skip)
//
// Ladder: R2 53.6 | R3 (1KB@8w) 56.9 | R5 (nt) 57.7 | R6 (512B@16w) 52.1 | R7 (pk-fma) 52.2 null
// R8: fuse coeff-producer into the main kernel with a device-scope counter barrier;
//     removes kernel-1 launch + gap (~4 us of fixed overhead). Consumer body = R6 verbatim.
//     Co-residency: 1024 blocks, __launch_bounds__(256,8) => VGPR<=64, LDS 16.7KB
//     => >=8 blocks/CU capacity, all 1024 resident at dispatch; produce-before-spin.

#define IN_CH 512
#define OUT_CH 3
#define NPIX 16384    // 128*128
#define NB 8

__global__ __launch_bounds__(256, 8) void fused_kernel(
    const float* __restrict__ x, const float* __restrict__ w,
    const float* __restrict__ skip, const float* __restrict__ aw,
    const float* __restrict__ ab, const float* __restrict__ wt,
    const float* __restrict__ bias, float* __restrict__ out,
    int* __restrict__ ctr, float* __restrict__ coeff) {
  const int bid = blockIdx.x;
  const int tid = threadIdx.x;
  const int b   = bid >> 7;   // batch, 8
  const int g   = bid & 127;  // pixel group (consumer) / row group (producer)
  const int p0  = g * 128;

  __shared__ float wv[512];
  __shared__ float lds_c[8 * 64 * 4];   // 8 KB
  __shared__ float red[4][32][13];      // 6.5 KB

  // ---------- phase 1: produce 4 coeff rows for batch b (rows g*4 .. g*4+3) ----------
  wv[tid]       = w[b * 512 + tid];
  wv[tid + 256] = w[b * 512 + 256 + tid];
  __syncthreads();
  const int wave = tid >> 6, lane = tid & 63;
  {
    const int i = g * 4 + wave;               // one row per wave
    const float* row = aw + (size_t)i * 512;
    float s = 0.f;
    #pragma unroll
    for (int k = 0; k < 8; ++k) s += row[lane + 64 * k] * wv[lane + 64 * k];
    #pragma unroll
    for (int off = 32; off >= 1; off >>= 1) s += __shfl_xor(s, off, 64);
    if (lane == 0) {
      float v = s * (1.0f / sqrtf(512.0f)) + ab[i];
      v = (v > 0.f ? v : 0.2f * v) * 1.41421356237f;   // lrelu * sqrt(2)
      #pragma unroll
      for (int o = 0; o < OUT_CH; ++o)
        coeff[b * (OUT_CH * IN_CH) + o * IN_CH + i] =
            wt[o * IN_CH + i] * (1.0f / 512.0f) * v;
    }
  }
  __threadfence();          // release coeff stores to agent scope
  __syncthreads();
  if (tid == 0)
    __hip_atomic_fetch_add(ctr, 1, __ATOMIC_RELEASE, __HIP_MEMORY_SCOPE_AGENT);

  // ---------- phase 2: skip upsample early (coeff-independent; hides spin) ----------
  float up[3] = {0.f, 0.f, 0.f};
  if (tid < 128) {
    const int p = p0 + tid;
    const int yy = p >> 7, xx = p & 127;
    int iy0, ix0; float wy0, wy1, wx0, wx1;
    if (yy & 1) { iy0 = (yy - 1) >> 1; wy0 = 3.f; wy1 = 1.f; }
    else        { iy0 = (yy >> 1) - 1; wy0 = 1.f; wy1 = 3.f; }
    if (xx & 1) { ix0 = (xx - 1) >> 1; wx0 = 3.f; wx1 = 1.f; }
    else        { ix0 = (xx >> 1) - 1; wx0 = 1.f; wx1 = 3.f; }
    const float wyx00 = wy0 * wx0 * (1.f / 16.f), wyx01 = wy0 * wx1 * (1.f / 16.f);
    const float wyx10 = wy1 * wx0 * (1.f / 16.f), wyx11 = wy1 * wx1 * (1.f / 16.f);
    const bool y0ok = (iy0 >= 0), y1ok = (iy0 + 1 < 64);
    const bool x0ok = (ix0 >= 0), x1ok = (ix0 + 1 < 64);
    #pragma unroll
    for (int o = 0; o < OUT_CH; ++o) {
      const float* sp = skip + ((size_t)(b * OUT_CH + o)) * 4096;
      float s00 = (y0ok && x0ok) ? sp[iy0 * 64 + ix0]           : 0.f;
      float s01 = (y0ok && x1ok) ? sp[iy0 * 64 + ix0 + 1]       : 0.f;
      float s10 = (y1ok && x0ok) ? sp[(iy0 + 1) * 64 + ix0]     : 0.f;
      float s11 = (y1ok && x1ok) ? sp[(iy0 + 1) * 64 + ix0 + 1] : 0.f;
      up[o] = wyx00 * s00 + wyx01 * s01 + wyx10 * s10 + wyx11 * s11;
    }
  }

  // ---------- phase 3: wait for all 1024 producers ----------
  if (tid == 0) {
    while (__hip_atomic_load(ctr, __ATOMIC_ACQUIRE, __HIP_MEMORY_SCOPE_AGENT) < 1024) {
      __builtin_amdgcn_s_sleep(16);
    }
  }
  __syncthreads();
  __threadfence();          // acquire: invalidate caches before reading coeff

  // ---------- phase 4: consumer body (R6 verbatim) ----------
  const int col   = tid & 31;   // float4 column within 128-pixel group
  const int split = tid >> 5;   // channel split, 64 channels each

  for (int idx = tid; idx < 2048; idx += 256) {
    const int s = idx >> 8, rem = idx & 255, k = rem >> 2, o = rem & 3;
    lds_c[idx] = (o < 3)
        ? coeff[b * (OUT_CH * IN_CH) + o * IN_CH + s * 64 + k]
        : 0.f;
  }
  __syncthreads();

  const float* xp = x + ((size_t)(b * IN_CH + split * 64)) * NPIX + p0 + col * 4;
  const float* cp = lds_c + split * 256;

  float acc[12];
  #pragma unroll
  for (int j = 0; j < 12; ++j) acc[j] = 0.f;

  #pragma unroll 4
  for (int k = 0; k < 64; ++k) {
    float4 xv = *reinterpret_cast<const float4*>(xp + (size_t)k * NPIX);
    float4 c4 = *reinterpret_cast<const float4*>(cp + k * 4);
    acc[0] += c4.x * xv.x; acc[1]  += c4.x * xv.y; acc[2]  += c4.x * xv.z; acc[3]  += c4.x * xv.w;
    acc[4] += c4.y * xv.x; acc[5]  += c4.y * xv.y; acc[6]  += c4.y * xv.z; acc[7]  += c4.y * xv.w;
    acc[8] += c4.z * xv.x; acc[9]  += c4.z * xv.y; acc[10] += c4.z * xv.z; acc[11] += c4.z * xv.w;
  }

  // fold the 2 splits within each wave (lanes differ by 32)
  #pragma unroll
  for (int j = 0; j < 12; ++j) acc[j] += __shfl_xor(acc[j], 32, 64);

  if (lane < 32) {
    #pragma unroll
    for (int j = 0; j < 12; ++j) red[wave][lane][j] = acc[j];
  }
  __syncthreads();

  // epilogue: threads 0..127 -> pixel p0+tid, 3 channels
  if (tid < 128) {
    const int c = tid >> 2, s = tid & 3;
    #pragma unroll
    for (int o = 0; o < OUT_CH; ++o) {
      const int j = o * 4 + s;
      float v = red[0][c][j] + red[1][c][j] + red[2][c][j] + red[3][c][j] + bias[o];
      v = fminf(fmaxf(v, -256.f), 256.f);
      out[((size_t)(b * OUT_CH + o)) * NPIX + p0 + tid] = v + up[o];
    }
  }
}

extern "C" void kernel_launch(void* const* d_in, const int* in_sizes, int n_in,
                              void* d_out, int out_size, void* d_ws, size_t ws_size,
                              hipStream_t stream) {
  const float* x        = (const float*)d_in[0];
  const float* w        = (const float*)d_in[1];
  const float* skip     = (const float*)d_in[2];
  const float* affine_w = (const float*)d_in[3];
  const float* affine_b = (const float*)d_in[4];
  const float* weight   = (const float*)d_in[5];
  const float* bias     = (const float*)d_in[6];
  float* out   = (float*)d_out;

  int*   ctr   = (int*)d_ws;                        // 4 B counter
  float* coeff = (float*)((char*)d_ws + 256);       // 48 KB coeff, 256B-aligned

  hipMemsetAsync(ctr, 0, sizeof(int), stream);      // graph-legal, deterministic
  fused_kernel<<<NB * 128, 256, 0, stream>>>(
      x, w, skip, affine_w, affine_b, weight, bias, out, ctr, coeff);
}

// Round 9
// 52.041 us; speedup vs baseline: 3.9813x; 3.9813x over previous
//
#include <hip/hip_runtime.h>
#include <math.h>

// ToRGB: y[b,o,p] = clip( sum_i coeff[b,o,i]*x[b,i,p] + bias[o], +-256 ) + upsample2(skip)
// x: (8,512,128,128) f32; out: (8,3,128,128) f32
//
// Ladder: R2 (256B,32w) 53.6 | R3 (1KB,8w) 56.9 | R5 (nt) 57.7 | R6 (512B,16w) 52.1
//         R7 (pk-fma/32b-addr) null | R8 (fused global barrier) 207 -- REVERTED
// R9: last corner of the (chunk x occupancy) grid: 512B chunks AND 32 waves/CU.
//     512-thread blocks (32 cols x 16 splits), 1024 blocks = 4 blk/CU x 8 waves.

#define IN_CH 512
#define OUT_CH 3
#define NPIX 16384    // 128*128
#define NB 8

// ---------------- Kernel 1: styles -> coeff (tiny) ----------------
__global__ __launch_bounds__(256) void coeff_kernel(
    const float* __restrict__ w, const float* __restrict__ aw,
    const float* __restrict__ ab, const float* __restrict__ wt,
    float* __restrict__ coeff) {
  const int b  = blockIdx.x >> 6;   // 8 batches
  const int rg = blockIdx.x & 63;   // 64 row-groups of 8 rows
  const int tid = threadIdx.x;
  __shared__ float wv[512];
  wv[tid]       = w[b * 512 + tid];
  wv[tid + 256] = w[b * 512 + 256 + tid];
  __syncthreads();
  const int wave = tid >> 6, lane = tid & 63;
  const float gain = 1.0f / sqrtf(512.0f);
  #pragma unroll
  for (int r = 0; r < 2; ++r) {
    const int i = rg * 8 + wave * 2 + r;
    const float* row = aw + (size_t)i * 512;
    float s = 0.f;
    #pragma unroll
    for (int k = 0; k < 8; ++k) s += row[lane + 64 * k] * wv[lane + 64 * k];
    #pragma unroll
    for (int off = 32; off >= 1; off >>= 1) s += __shfl_xor(s, off, 64);
    if (lane == 0) {
      float v = s * gain + ab[i];
      v = (v > 0.f ? v : 0.2f * v) * 1.41421356237f;  // lrelu * sqrt(2)
      #pragma unroll
      for (int o = 0; o < OUT_CH; ++o)
        coeff[b * (OUT_CH * IN_CH) + o * IN_CH + i] =
            wt[o * IN_CH + i] * (1.0f / 512.0f) * v;
    }
  }
}

// ---------------- Kernel 2: main reduction + epilogue ----------------
// grid: 8 batches * 128 pixel-groups (128 px each). block: 512 = 32 cols(x4 px) * 16 splits(32 ch)
// 512B contiguous per split-chunk; 4 blocks/CU * 8 waves = 32 waves/CU (max occupancy).
__global__ __launch_bounds__(512, 8) void main_kernel(
    const float* __restrict__ x, const float* __restrict__ coeff,
    const float* __restrict__ bias, const float* __restrict__ skip,
    float* __restrict__ out) {
  const int b   = blockIdx.x >> 7;
  const int g   = blockIdx.x & 127;
  const int p0  = g * 128;
  const int tid = threadIdx.x;
  const int col   = tid & 31;   // float4 column within 128-pixel group
  const int split = tid >> 5;   // channel split, 32 channels each (16 splits)

  // coeff staged [split][k][4] -> one ds_read_b128 per k (wave-uniform broadcast)
  __shared__ float lds_c[16 * 32 * 4];  // 8 KB
  for (int idx = tid; idx < 2048; idx += 512) {
    const int s = idx >> 7, rem = idx & 127, k = rem >> 2, o = rem & 3;
    lds_c[idx] = (o < 3)
        ? coeff[b * (OUT_CH * IN_CH) + o * IN_CH + s * 32 + k]
        : 0.f;
  }

  // ---- skip upsample EARLY (hides skip HBM latency under main loop) ----
  float up[3] = {0.f, 0.f, 0.f};
  if (tid < 128) {
    const int p = p0 + tid;
    const int yy = p >> 7, xx = p & 127;
    int iy0, ix0; float wy0, wy1, wx0, wx1;
    if (yy & 1) { iy0 = (yy - 1) >> 1; wy0 = 3.f; wy1 = 1.f; }
    else        { iy0 = (yy >> 1) - 1; wy0 = 1.f; wy1 = 3.f; }
    if (xx & 1) { ix0 = (xx - 1) >> 1; wx0 = 3.f; wx1 = 1.f; }
    else        { ix0 = (xx >> 1) - 1; wx0 = 1.f; wx1 = 3.f; }
    const float wyx00 = wy0 * wx0 * (1.f / 16.f), wyx01 = wy0 * wx1 * (1.f / 16.f);
    const float wyx10 = wy1 * wx0 * (1.f / 16.f), wyx11 = wy1 * wx1 * (1.f / 16.f);
    const bool y0ok = (iy0 >= 0), y1ok = (iy0 + 1 < 64);
    const bool x0ok = (ix0 >= 0), x1ok = (ix0 + 1 < 64);
    #pragma unroll
    for (int o = 0; o < OUT_CH; ++o) {
      const float* sp = skip + ((size_t)(b * OUT_CH + o)) * 4096;
      float s00 = (y0ok && x0ok) ? sp[iy0 * 64 + ix0]           : 0.f;
      float s01 = (y0ok && x1ok) ? sp[iy0 * 64 + ix0 + 1]       : 0.f;
      float s10 = (y1ok && x0ok) ? sp[(iy0 + 1) * 64 + ix0]     : 0.f;
      float s11 = (y1ok && x1ok) ? sp[(iy0 + 1) * 64 + ix0 + 1] : 0.f;
      up[o] = wyx00 * s00 + wyx01 * s01 + wyx10 * s10 + wyx11 * s11;
    }
  }

  __syncthreads();

  const float* xp = x + ((size_t)(b * IN_CH + split * 32)) * NPIX + p0 + col * 4;
  const float* cp = lds_c + split * 128;

  float acc[12];
  #pragma unroll
  for (int j = 0; j < 12; ++j) acc[j] = 0.f;

  #pragma unroll 8
  for (int k = 0; k < 32; ++k) {
    float4 xv = *reinterpret_cast<const float4*>(xp + (size_t)k * NPIX);
    float4 c4 = *reinterpret_cast<const float4*>(cp + k * 4);
    acc[0] += c4.x * xv.x; acc[1]  += c4.x * xv.y; acc[2]  += c4.x * xv.z; acc[3]  += c4.x * xv.w;
    acc[4] += c4.y * xv.x; acc[5]  += c4.y * xv.y; acc[6]  += c4.y * xv.z; acc[7]  += c4.y * xv.w;
    acc[8] += c4.z * xv.x; acc[9]  += c4.z * xv.y; acc[10] += c4.z * xv.z; acc[11] += c4.z * xv.w;
  }

  // ---- fold the 2 splits within each wave (lanes differ by 32) ----
  #pragma unroll
  for (int j = 0; j < 12; ++j) acc[j] += __shfl_xor(acc[j], 32, 64);

  // lanes 0-31 of each of the 8 waves hold sums over 2 splits x 32 cols
  __shared__ float red[8][32][13];  // stride 13: conflict-free (<=2-way in epilogue)
  const int wave = tid >> 6, lane = tid & 63;
  if (lane < 32) {
    #pragma unroll
    for (int j = 0; j < 12; ++j) red[wave][lane][j] = acc[j];
  }
  __syncthreads();

  // epilogue: threads 0..127 -> pixel p0+tid, 3 channels
  if (tid < 128) {
    const int c = tid >> 2, s = tid & 3;
    #pragma unroll
    for (int o = 0; o < OUT_CH; ++o) {
      const int j = o * 4 + s;
      float v = bias[o];
      #pragma unroll
      for (int wv = 0; wv < 8; ++wv) v += red[wv][c][j];
      v = fminf(fmaxf(v, -256.f), 256.f);
      out[((size_t)(b * OUT_CH + o)) * NPIX + p0 + tid] = v + up[o];
    }
  }
}

extern "C" void kernel_launch(void* const* d_in, const int* in_sizes, int n_in,
                              void* d_out, int out_size, void* d_ws, size_t ws_size,
                              hipStream_t stream) {
  const float* x        = (const float*)d_in[0];
  const float* w        = (const float*)d_in[1];
  const float* skip     = (const float*)d_in[2];
  const float* affine_w = (const float*)d_in[3];
  const float* affine_b = (const float*)d_in[4];
  const float* weight   = (const float*)d_in[5];
  const float* bias     = (const float*)d_in[6];
  float* out   = (float*)d_out;
  float* coeff = (float*)d_ws;  // 8*3*512 floats = 48 KB

  coeff_kernel<<<512, 256, 0, stream>>>(w, affine_w, affine_b, weight, coeff);
  main_kernel<<<NB * 128, 512, 0, stream>>>(x, coeff, bias, skip, out);
}